// Round 1
// baseline (1509.427 us; speedup 1.0000x reference)
//
#include <hip/hip_runtime.h>
#include <hip/hip_bf16.h>

#define B_   8
#define LQ   3136
#define LK   784
#define LKP  832      // padded K/V rows in workspace (64-chunk staging reads up to 832)
#define C_   192
#define EPSV 1e-5f

// ---------------- Kernel 1: depthwise 3x3 stride-1 + BN (Q path) ----------------
__global__ __launch_bounds__(256) void dw_s1_kernel(
    const float* __restrict__ x, const float* __restrict__ dw,
    const float* __restrict__ sc, const float* __restrict__ bi,
    const float* __restrict__ me, const float* __restrict__ va,
    float* __restrict__ y)
{
  int g = blockIdx.x * 256 + threadIdx.x;
  if (g >= B_ * 56 * 56 * C_) return;
  int c = g % C_; int t = g / C_;
  int xx = t % 56; int yy = (t / 56) % 56; int b = t / (56 * 56);
  float s = 0.f;
#pragma unroll
  for (int dy = 0; dy < 3; ++dy) {
    int iy = yy + dy - 1;
    if (iy < 0 || iy >= 56) continue;
#pragma unroll
    for (int dx = 0; dx < 3; ++dx) {
      int ix = xx + dx - 1;
      if (ix < 0 || ix >= 56) continue;
      s += x[((long long)((b * 56 + iy) * 56 + ix)) * C_ + c] * dw[(dy * 3 + dx) * C_ + c];
    }
  }
  float scale = sc[c] * rsqrtf(va[c] + EPSV);
  y[g] = (s - me[c]) * scale + bi[c];
}

// ---------------- Kernel 2: depthwise 3x3 stride-2 + BN, fused K & V ----------------
__global__ __launch_bounds__(256) void dw_s2_kv_kernel(
    const float* __restrict__ x,
    const float* __restrict__ kdw_w, const float* __restrict__ ksc, const float* __restrict__ kbi,
    const float* __restrict__ kme,  const float* __restrict__ kva,
    const float* __restrict__ vdw_w, const float* __restrict__ vsc, const float* __restrict__ vbi,
    const float* __restrict__ vme,  const float* __restrict__ vva,
    float* __restrict__ ky, float* __restrict__ vy)
{
  int g = blockIdx.x * 256 + threadIdx.x;
  if (g >= B_ * 28 * 28 * C_) return;
  int c = g % C_; int t = g / C_;
  int xo = t % 28; int yo = (t / 28) % 28; int b = t / (28 * 28);
  float sk = 0.f, sv = 0.f;
#pragma unroll
  for (int dy = 0; dy < 3; ++dy) {
    int iy = yo * 2 + dy;            // SAME stride-2: pad_lo = 0, pad_hi = 1
    if (iy >= 56) continue;
#pragma unroll
    for (int dx = 0; dx < 3; ++dx) {
      int ix = xo * 2 + dx;
      if (ix >= 56) continue;
      float xv = x[((long long)((b * 56 + iy) * 56 + ix)) * C_ + c];
      sk += xv * kdw_w[(dy * 3 + dx) * C_ + c];
      sv += xv * vdw_w[(dy * 3 + dx) * C_ + c];
    }
  }
  float kscale = ksc[c] * rsqrtf(kva[c] + EPSV);
  float vscale = vsc[c] * rsqrtf(vva[c] + EPSV);
  ky[g] = (sk - kme[c]) * kscale + kbi[c];
  vy[g] = (sv - vme[c]) * vscale + vbi[c];
}

// ---------------- Kernel 3: shared GEMM, Y[M x 192] = X[M x 192] * W[192 x 192] * scale ----------------
// Output remap: row G -> batch b = G/IBR, local l = G%IBR, address b*OBS + l*192 + n.
__global__ __launch_bounds__(256) void gemm192_kernel(
    const float* __restrict__ X, const float* __restrict__ W,
    float* __restrict__ Y, int IBR, long long OBS, float scale)
{
  __shared__ float Xt[32][68];   // [kk][m], padded
  __shared__ float Ws[32][68];   // [kk][n], padded
  const int tid = threadIdx.x;
  const long long R0 = (long long)blockIdx.x * 64;
  const int N0 = blockIdx.y * 64;
  const int Mg = tid & 15, Ng = tid >> 4;
  float acc[4][4] = {};
  for (int k0 = 0; k0 < 192; k0 += 32) {
    int row = tid >> 3, kq = (tid & 7) * 4;
    float4 a0 = *(const float4*)&X[(R0 + row) * C_ + k0 + kq];
    float4 a1 = *(const float4*)&X[(R0 + row + 32) * C_ + k0 + kq];
    int kr = tid >> 4, nq = (tid & 15) * 4;
    float4 w0 = *(const float4*)&W[(k0 + kr) * C_ + N0 + nq];
    float4 w1 = *(const float4*)&W[(k0 + kr + 16) * C_ + N0 + nq];
    __syncthreads();   // protect previous iteration's reads
    Xt[kq + 0][row] = a0.x; Xt[kq + 1][row] = a0.y; Xt[kq + 2][row] = a0.z; Xt[kq + 3][row] = a0.w;
    Xt[kq + 0][row + 32] = a1.x; Xt[kq + 1][row + 32] = a1.y; Xt[kq + 2][row + 32] = a1.z; Xt[kq + 3][row + 32] = a1.w;
    *(float4*)&Ws[kr][nq] = w0;
    *(float4*)&Ws[kr + 16][nq] = w1;
    __syncthreads();
#pragma unroll 8
    for (int kk = 0; kk < 32; ++kk) {
      float4 av = *(const float4*)&Xt[kk][Mg * 4];
      float4 bv = *(const float4*)&Ws[kk][Ng * 4];
      float aa[4] = {av.x, av.y, av.z, av.w};
      float bb[4] = {bv.x, bv.y, bv.z, bv.w};
#pragma unroll
      for (int r = 0; r < 4; ++r)
#pragma unroll
        for (int j = 0; j < 4; ++j)
          acc[r][j] += aa[r] * bb[j];
    }
  }
#pragma unroll
  for (int r = 0; r < 4; ++r) {
    long long G = R0 + Mg * 4 + r;
    int bb_ = (int)(G / IBR); int l = (int)(G % IBR);
    float4 o;
    o.x = acc[r][0] * scale; o.y = acc[r][1] * scale;
    o.z = acc[r][2] * scale; o.w = acc[r][3] * scale;
    *(float4*)&Y[(long long)bb_ * OBS + (long long)l * C_ + N0 + Ng * 4] = o;
  }
}

// ---------------- Kernel 4: fused head-mixed attention ----------------
// Per block: batch b, 32 q rows. Two-pass softmax (no max-subtract; scores are O(0.1), clamp guards).
// Row mapping: logical m = h*32 + qq with qq = Mg + 16t; thread owns rows r=0..5 -> (h=r>>1, t=r&1),
// physical LDS column p = 6*Mg + r. Pre/post head mixes are thread-local.
__device__ __forceinline__ void qk_tile(const float* __restrict__ qb,
                                        const float* __restrict__ kb0,
                                        const float* __restrict__ kb1,
                                        const float* __restrict__ kb2,
                                        float s[6][4])
{
#pragma unroll 4
  for (int d = 0; d < 64; ++d) {
    float4 k0v = *(const float4*)&kb0[d * 68];
    float4 k1v = *(const float4*)&kb1[d * 68];
    float4 k2v = *(const float4*)&kb2[d * 68];
    float a0 = qb[d * 97 + 0], a1 = qb[d * 97 + 1], a2 = qb[d * 97 + 2];
    float a3 = qb[d * 97 + 3], a4 = qb[d * 97 + 4], a5 = qb[d * 97 + 5];
    s[0][0] += a0 * k0v.x; s[0][1] += a0 * k0v.y; s[0][2] += a0 * k0v.z; s[0][3] += a0 * k0v.w;
    s[1][0] += a1 * k0v.x; s[1][1] += a1 * k0v.y; s[1][2] += a1 * k0v.z; s[1][3] += a1 * k0v.w;
    s[2][0] += a2 * k1v.x; s[2][1] += a2 * k1v.y; s[2][2] += a2 * k1v.z; s[2][3] += a2 * k1v.w;
    s[3][0] += a3 * k1v.x; s[3][1] += a3 * k1v.y; s[3][2] += a3 * k1v.z; s[3][3] += a3 * k1v.w;
    s[4][0] += a4 * k2v.x; s[4][1] += a4 * k2v.y; s[4][2] += a4 * k2v.z; s[4][3] += a4 * k2v.w;
    s[5][0] += a5 * k2v.x; s[5][1] += a5 * k2v.y; s[5][2] += a5 * k2v.z; s[5][3] += a5 * k2v.w;
  }
}

__global__ __launch_bounds__(256, 1) void attn_kernel(
    const float* __restrict__ Q,   // [B][3136][192], pre-scaled by 1/8
    const float* __restrict__ Kw,  // [B][832][192]
    const float* __restrict__ Vw,  // [B][832][192]
    const float* __restrict__ pre, const float* __restrict__ post,
    float* __restrict__ O)         // [B][3136][192]
{
  extern __shared__ float smf[];
  float* Qt   = smf;                    // [64][97]   d-major, permuted cols
  float* Kt   = smf + 6208;             // [3][64][68] (h, d, kc)
  float* Vc   = Kt + 13056;             // [64][192]
  float* Pt   = Vc + 12288;             // [64][97]
  float* Lred = Pt + 6208;              // [96][16]
  float* Linv = Lred + 1536;            // [96]

  const int tid = threadIdx.x;
  const int b  = blockIdx.x / 98;
  const int q0 = (blockIdx.x % 98) * 32;
  const int Mg = tid & 15;
  const int Kg = tid >> 4;
  const int c4 = Kg * 4;    // kc offset in QK, d offset in PV
  const int p0 = Mg * 6;

  float preM[9], postM[9];
#pragma unroll
  for (int i = 0; i < 9; ++i) { preM[i] = pre[i]; postM[i] = post[i]; }

  // ---- stage Q tile (once) ----
  for (int i = tid; i < 32 * 48; i += 256) {
    int qq = i & 31, cq = i >> 5;
    float4 v = *(const float4*)&Q[((long long)(b * LQ + q0 + qq)) * C_ + cq * 4];
    int c = cq * 4; int h = c >> 6; int d = c & 63;
    int p = 6 * (qq & 15) + 2 * h + (qq >> 4);
    Qt[(d + 0) * 97 + p] = v.x;
    Qt[(d + 1) * 97 + p] = v.y;
    Qt[(d + 2) * 97 + p] = v.z;
    Qt[(d + 3) * 97 + p] = v.w;
  }

  const float* qb  = Qt + p0;
  const float* kb0 = Kt + c4;
  const float* kb1 = Kt + 4352 + c4;
  const float* kb2 = Kt + 8704 + c4;

  float lp[3][2] = {};

  // ---- sweep 1: softmax denominators ----
  for (int k0 = 0; k0 < LK; k0 += 64) {
    __syncthreads();
    for (int i = tid; i < 64 * 48; i += 256) {   // stage K chunk, lanes walk kk -> conflict-free LDS writes
      int kk = i & 63, cq = i >> 6;
      float4 v = *(const float4*)&Kw[((long long)(b * LKP + k0 + kk)) * C_ + cq * 4];
      int c = cq * 4; int h = c >> 6; int d = c & 63;
      float* kb = &Kt[h * 4352 + d * 68 + kk];
      kb[0] = v.x; kb[68] = v.y; kb[136] = v.z; kb[204] = v.w;
    }
    __syncthreads();
    float s[6][4] = {};
    qk_tile(qb, kb0, kb1, kb2, s);
#pragma unroll
    for (int t = 0; t < 2; ++t) {
#pragma unroll
      for (int j = 0; j < 4; ++j) {
        if ((k0 + c4 + j) >= LK) continue;
        float s0 = s[0 + t][j], s1 = s[2 + t][j], s2 = s[4 + t][j];
#pragma unroll
        for (int i = 0; i < 3; ++i) {
          float sm = preM[i] * s0 + preM[3 + i] * s1 + preM[6 + i] * s2;
          sm = fminf(fmaxf(sm, -50.f), 50.f);
          lp[i][t] += __expf(sm);
        }
      }
    }
  }
  __syncthreads();
#pragma unroll
  for (int i = 0; i < 3; ++i)
#pragma unroll
    for (int t = 0; t < 2; ++t)
      Lred[(i * 32 + Mg + 16 * t) * 16 + Kg] = lp[i][t];
  __syncthreads();
  if (tid < 96) {
    float l = 0.f;
#pragma unroll
    for (int g = 0; g < 16; ++g) l += Lred[tid * 16 + g];
    Linv[tid] = 1.0f / l;
  }
  __syncthreads();
  float linvr[3][2];
#pragma unroll
  for (int i = 0; i < 3; ++i)
#pragma unroll
    for (int t = 0; t < 2; ++t)
      linvr[i][t] = Linv[i * 32 + Mg + 16 * t];

  // ---- sweep 2: P and PV ----
  float o[6][4] = {};
  for (int k0 = 0; k0 < LK; k0 += 64) {
    __syncthreads();
    for (int i = tid; i < 64 * 48; i += 256) {   // stage K
      int kk = i & 63, cq = i >> 6;
      float4 v = *(const float4*)&Kw[((long long)(b * LKP + k0 + kk)) * C_ + cq * 4];
      int c = cq * 4; int h = c >> 6; int d = c & 63;
      float* kb = &Kt[h * 4352 + d * 68 + kk];
      kb[0] = v.x; kb[68] = v.y; kb[136] = v.z; kb[204] = v.w;
    }
    for (int i = tid; i < 64 * 48; i += 256) {   // stage V (natural layout)
      int kk = i / 48, cq = i % 48;
      float4 v = *(const float4*)&Vw[((long long)(b * LKP + k0 + kk)) * C_ + cq * 4];
      *(float4*)&Vc[kk * 192 + cq * 4] = v;
    }
    __syncthreads();
    float s[6][4] = {};
    qk_tile(qb, kb0, kb1, kb2, s);
#pragma unroll
    for (int t = 0; t < 2; ++t) {
#pragma unroll
      for (int j = 0; j < 4; ++j) {
        float e0 = 0.f, e1 = 0.f, e2 = 0.f;
        if ((k0 + c4 + j) < LK) {
          float s0 = s[0 + t][j], s1 = s[2 + t][j], s2 = s[4 + t][j];
          float x0 = preM[0] * s0 + preM[3] * s1 + preM[6] * s2;
          float x1 = preM[1] * s0 + preM[4] * s1 + preM[7] * s2;
          float x2 = preM[2] * s0 + preM[5] * s1 + preM[8] * s2;
          e0 = __expf(fminf(fmaxf(x0, -50.f), 50.f)) * linvr[0][t];
          e1 = __expf(fminf(fmaxf(x1, -50.f), 50.f)) * linvr[1][t];
          e2 = __expf(fminf(fmaxf(x2, -50.f), 50.f)) * linvr[2][t];
        }
        int col = (c4 + j) * 97 + p0;
#pragma unroll
        for (int h = 0; h < 3; ++h) {
          float pm = postM[h] * e0 + postM[3 + h] * e1 + postM[6 + h] * e2;
          Pt[col + 2 * h + t] = pm;   // zero for masked tail -> PV adds 0
        }
      }
    }
    __syncthreads();
#pragma unroll 2
    for (int kk = 0; kk < 64; ++kk) {
      const float* vrow = &Vc[kk * 192 + c4];
      float4 v0 = *(const float4*)&vrow[0];
      float4 v1 = *(const float4*)&vrow[64];
      float4 v2 = *(const float4*)&vrow[128];
      const float* pp = &Pt[kk * 97 + p0];
      float pa = pp[0], pb = pp[1], pc = pp[2], pd = pp[3], pe = pp[4], pf = pp[5];
      o[0][0] += pa * v0.x; o[0][1] += pa * v0.y; o[0][2] += pa * v0.z; o[0][3] += pa * v0.w;
      o[1][0] += pb * v0.x; o[1][1] += pb * v0.y; o[1][2] += pb * v0.z; o[1][3] += pb * v0.w;
      o[2][0] += pc * v1.x; o[2][1] += pc * v1.y; o[2][2] += pc * v1.z; o[2][3] += pc * v1.w;
      o[3][0] += pd * v1.x; o[3][1] += pd * v1.y; o[3][2] += pd * v1.z; o[3][3] += pd * v1.w;
      o[4][0] += pe * v2.x; o[4][1] += pe * v2.y; o[4][2] += pe * v2.z; o[4][3] += pe * v2.w;
      o[5][0] += pf * v2.x; o[5][1] += pf * v2.y; o[5][2] += pf * v2.z; o[5][3] += pf * v2.w;
    }
  }
#pragma unroll
  for (int r = 0; r < 6; ++r) {
    int h = r >> 1, qq = Mg + 16 * (r & 1);
    float4 ov; ov.x = o[r][0]; ov.y = o[r][1]; ov.z = o[r][2]; ov.w = o[r][3];
    *(float4*)&O[((long long)(b * LQ + q0 + qq)) * C_ + h * 64 + c4] = ov;
  }
}

extern "C" void kernel_launch(void* const* d_in, const int* in_sizes, int n_in,
                              void* d_out, int out_size, void* d_ws, size_t ws_size,
                              hipStream_t stream) {
  (void)in_sizes; (void)n_in; (void)out_size; (void)ws_size;
  const float* inq  = (const float*)d_in[0];
  const float* inkv = (const float*)d_in[1];
  const float* q_dw = (const float*)d_in[2];
  const float* q_sc = (const float*)d_in[3];
  const float* q_bi = (const float*)d_in[4];
  const float* q_me = (const float*)d_in[5];
  const float* q_va = (const float*)d_in[6];
  const float* q_pw = (const float*)d_in[7];
  const float* k_dw = (const float*)d_in[8];
  const float* k_sc = (const float*)d_in[9];
  const float* k_bi = (const float*)d_in[10];
  const float* k_me = (const float*)d_in[11];
  const float* k_va = (const float*)d_in[12];
  const float* k_pw = (const float*)d_in[13];
  const float* v_dw = (const float*)d_in[14];
  const float* v_sc = (const float*)d_in[15];
  const float* v_bi = (const float*)d_in[16];
  const float* v_me = (const float*)d_in[17];
  const float* v_va = (const float*)d_in[18];
  const float* v_pw = (const float*)d_in[19];
  const float* preS  = (const float*)d_in[20];
  const float* postS = (const float*)d_in[21];
  const float* outk  = (const float*)d_in[22];
  float* out = (float*)d_out;
  float* ws  = (float*)d_ws;

  // workspace layout (floats); total 14,598,144 floats = 58.4 MB
  float* qdw = ws;                   // [8][3136][192]   (reused as attn output later)
  float* qs  = qdw + 4816896;        // [8][3136][192]
  float* kdw = qs + 4816896;         // [8][784][192]
  float* vdw = kdw + 1204224;        // [8][784][192]
  float* kp  = vdw + 1204224;        // [8][832][192]  padded
  float* vp  = kp + 1277952;         // [8][832][192]  padded
  float* attn = qdw;                 // reuse (qdw consumed before attn is written)

  dw_s1_kernel<<<18816, 256, 0, stream>>>(inq, q_dw, q_sc, q_bi, q_me, q_va, qdw);
  dw_s2_kv_kernel<<<4704, 256, 0, stream>>>(inkv, k_dw, k_sc, k_bi, k_me, k_va,
                                            v_dw, v_sc, v_bi, v_me, v_va, kdw, vdw);
  gemm192_kernel<<<dim3(392, 3), 256, 0, stream>>>(qdw, q_pw, qs, LQ, (long long)LQ * C_, 0.125f);
  gemm192_kernel<<<dim3(98, 3),  256, 0, stream>>>(kdw, k_pw, kp, LK, (long long)LKP * C_, 1.0f);
  gemm192_kernel<<<dim3(98, 3),  256, 0, stream>>>(vdw, v_pw, vp, LK, (long long)LKP * C_, 1.0f);
  attn_kernel<<<784, 256, 157568, stream>>>(qs, kp, vp, preS, postS, attn);
  gemm192_kernel<<<dim3(392, 3), 256, 0, stream>>>(attn, outk, out, LQ, (long long)LQ * C_, 1.0f);
}

// Round 4
// 407.386 us; speedup vs baseline: 3.7052x; 3.7052x over previous
//
#include <hip/hip_runtime.h>
#include <hip/hip_bf16.h>

#define B_   8
#define LQ   3136
#define LK   784
#define C_   192
#define EPSV 1e-5f
#define VTS  800                 // V^T row stride (cols padded 784->800, 16B-aligned)

using f32x4 = __attribute__((ext_vector_type(4))) float;
using s16x8 = __attribute__((ext_vector_type(8))) short;
using s16x4 = __attribute__((ext_vector_type(4))) short;
using us4   = __attribute__((ext_vector_type(4))) unsigned short;

#if __has_builtin(__builtin_amdgcn_mfma_f32_16x16x16bf16_1k)
#define HAVE_MFMA16 1
#else
#define HAVE_MFMA16 0
#endif

static __device__ __forceinline__ unsigned short f2bf(float x) {
  return __builtin_bit_cast(unsigned short, __float2bfloat16(x));
}

// ---------------- W prep: fp32 [192x192] -> bf16 transposed Wt[n][k], 4 matrices ----------------
__global__ __launch_bounds__(256) void wprep_kernel(
    const float* __restrict__ w0, const float* __restrict__ w1,
    const float* __restrict__ w2, const float* __restrict__ w3,
    short* __restrict__ Wt)
{
  int i = blockIdx.x * 256 + threadIdx.x;           // 4*36864 total, blocks don't straddle mats
  int m = i / 36864, r = i % 36864;
  int k = r / 192, n = r % 192;
  const float* W = (m == 0) ? w0 : (m == 1) ? w1 : (m == 2) ? w2 : w3;
  Wt[m * 36864 + n * 192 + k] = (short)f2bf(W[r]);
}

// ---------------- depthwise 3x3 stride-1 + BN -> bf16 (Q path), 4 channels/thread ----------------
__global__ __launch_bounds__(256) void dw_s1_kernel(
    const float* __restrict__ x, const float* __restrict__ dw,
    const float* __restrict__ sc, const float* __restrict__ bi,
    const float* __restrict__ me, const float* __restrict__ va,
    short* __restrict__ y)
{
  int g = blockIdx.x * 256 + threadIdx.x;           // B*3136*48 exact
  int c4 = (g % 48) * 4; int t = g / 48;
  int xx = t % 56, yy = (t / 56) % 56, b = t / 3136;
  float4 s = {0.f, 0.f, 0.f, 0.f};
#pragma unroll
  for (int dy = 0; dy < 3; ++dy) {
    int iy = yy + dy - 1;
    if (iy < 0 || iy >= 56) continue;
#pragma unroll
    for (int dx = 0; dx < 3; ++dx) {
      int ix = xx + dx - 1;
      if (ix < 0 || ix >= 56) continue;
      float4 xv = *(const float4*)&x[((size_t)((b * 56 + iy) * 56 + ix)) * C_ + c4];
      float4 wv = *(const float4*)&dw[(dy * 3 + dx) * C_ + c4];
      s.x += xv.x * wv.x; s.y += xv.y * wv.y; s.z += xv.z * wv.z; s.w += xv.w * wv.w;
    }
  }
  float4 scv = *(const float4*)&sc[c4]; float4 biv = *(const float4*)&bi[c4];
  float4 mev = *(const float4*)&me[c4]; float4 vav = *(const float4*)&va[c4];
  us4 o;
  o[0] = f2bf((s.x - mev.x) * (scv.x * rsqrtf(vav.x + EPSV)) + biv.x);
  o[1] = f2bf((s.y - mev.y) * (scv.y * rsqrtf(vav.y + EPSV)) + biv.y);
  o[2] = f2bf((s.z - mev.z) * (scv.z * rsqrtf(vav.z + EPSV)) + biv.z);
  o[3] = f2bf((s.w - mev.w) * (scv.w * rsqrtf(vav.w + EPSV)) + biv.w);
  *(us4*)&y[(size_t)t * C_ + c4] = o;
}

// ---------------- depthwise 3x3 stride-2 + BN, fused K & V -> bf16 ----------------
__global__ __launch_bounds__(256) void dw_s2_kv_kernel(
    const float* __restrict__ x,
    const float* __restrict__ kdw_w, const float* __restrict__ ksc, const float* __restrict__ kbi,
    const float* __restrict__ kme,  const float* __restrict__ kva,
    const float* __restrict__ vdw_w, const float* __restrict__ vsc, const float* __restrict__ vbi,
    const float* __restrict__ vme,  const float* __restrict__ vva,
    short* __restrict__ ky, short* __restrict__ vy)
{
  int g = blockIdx.x * 256 + threadIdx.x;           // B*784*48 exact
  int c4 = (g % 48) * 4; int t = g / 48;
  int xo = t % 28, yo = (t / 28) % 28, b = t / 784;
  float4 sk = {0.f, 0.f, 0.f, 0.f}, sv = {0.f, 0.f, 0.f, 0.f};
#pragma unroll
  for (int dy = 0; dy < 3; ++dy) {
    int iy = yo * 2 + dy;          // SAME stride-2: pad_lo=0, pad_hi=1
    if (iy >= 56) continue;
#pragma unroll
    for (int dx = 0; dx < 3; ++dx) {
      int ix = xo * 2 + dx;
      if (ix >= 56) continue;
      float4 xv = *(const float4*)&x[((size_t)((b * 56 + iy) * 56 + ix)) * C_ + c4];
      float4 kw = *(const float4*)&kdw_w[(dy * 3 + dx) * C_ + c4];
      float4 vw = *(const float4*)&vdw_w[(dy * 3 + dx) * C_ + c4];
      sk.x += xv.x * kw.x; sk.y += xv.y * kw.y; sk.z += xv.z * kw.z; sk.w += xv.w * kw.w;
      sv.x += xv.x * vw.x; sv.y += xv.y * vw.y; sv.z += xv.z * vw.z; sv.w += xv.w * vw.w;
    }
  }
  us4 ko, vo;
#pragma unroll
  for (int j = 0; j < 4; ++j) {
    int c = c4 + j;
    float skj = (j == 0) ? sk.x : (j == 1) ? sk.y : (j == 2) ? sk.z : sk.w;
    float svj = (j == 0) ? sv.x : (j == 1) ? sv.y : (j == 2) ? sv.z : sv.w;
    ko[j] = f2bf((skj - kme[c]) * (ksc[c] * rsqrtf(kva[c] + EPSV)) + kbi[c]);
    vo[j] = f2bf((svj - vme[c]) * (vsc[c] * rsqrtf(vva[c] + EPSV)) + vbi[c]);
  }
  *(us4*)&ky[(size_t)t * C_ + c4] = ko;
  *(us4*)&vy[(size_t)t * C_ + c4] = vo;
}

// ---------------- bf16 MFMA GEMM: Y[M x 192] = X[M x 192] * W[192 x 192], W given as Wt[n][k] bf16 ----
// MODE 0: Y bf16 [tok][n] * scale.  MODE 1: Y bf16 V^T: [b][n][784] stride VTS.  MODE 2: Y fp32 [tok][n].
template <int MODE>
__global__ __launch_bounds__(256) void gemm_bf16_kernel(
    const short* __restrict__ X, const short* __restrict__ Wt,
    void* __restrict__ Yv, float scale)
{
  const int tid = threadIdx.x;
  const int w = tid >> 6, lane = tid & 63;
  const int lr = lane & 15, lg = lane >> 4;
  const int rowA = blockIdx.x * 64 + w * 16 + lr;     // A-frag row (m = lane&15)
  const short* Xrow = X + (size_t)rowA * C_ + lg * 8;
  s16x8 af[6];
#pragma unroll
  for (int kk = 0; kk < 6; ++kk) af[kk] = *(const s16x8*)(Xrow + kk * 32);
  f32x4 acc[12] = {};
#pragma unroll
  for (int nt = 0; nt < 12; ++nt) {
    const short* wr = Wt + (size_t)(nt * 16 + lr) * C_ + lg * 8;
#pragma unroll
    for (int kk = 0; kk < 6; ++kk) {
      s16x8 bf_ = *(const s16x8*)(wr + kk * 32);
      acc[nt] = __builtin_amdgcn_mfma_f32_16x16x32_bf16(af[kk], bf_, acc[nt], 0, 0, 0);
    }
  }
  const int tok0 = blockIdx.x * 64 + w * 16 + lg * 4;  // D rows: (lane>>4)*4 + r
#pragma unroll
  for (int nt = 0; nt < 12; ++nt) {
    int n = nt * 16 + lr;
#pragma unroll
    for (int r = 0; r < 4; ++r) {
      int tok = tok0 + r;
      float v = acc[nt][r] * scale;
      if (MODE == 0) {
        ((short*)Yv)[(size_t)tok * C_ + n] = (short)f2bf(v);
      } else if (MODE == 1) {
        int b = tok / LK, k = tok - b * LK;
        ((short*)Yv)[(size_t)b * C_ * VTS + (size_t)n * VTS + k] = (short)f2bf(v);
      } else {
        ((float*)Yv)[(size_t)tok * C_ + n] = v;
      }
    }
  }
}

// ---------------- fused head-mixed attention, MFMA, no LDS, no syncthreads ----------------
// Wave handles 16 q-rows. S^T = mfma(K_tile, Q_tile) -> lane holds (q=lane&15, k=(lane>>4)*4+r),
// which IS the 16x16x16 PV A-fragment layout (j=r). Head mixes are thread-local.
__global__ __launch_bounds__(256) void attn_mfma_kernel(
    const short* __restrict__ Q,   // [B][3136][192] bf16, pre-scaled 1/8
    const short* __restrict__ K,   // [B][784][192] bf16
    const short* __restrict__ VT,  // [B][192][VTS] bf16 (cols 784..799 garbage, never read in primary)
    const float* __restrict__ pre, const float* __restrict__ post,
    short* __restrict__ Ob)        // [B][3136][192] bf16
{
  const int tid = threadIdx.x;
  const int w = tid >> 6, lane = tid & 63;
  const int lr = lane & 15, lg = lane >> 4;
  const int b = blockIdx.x / 49, qt = blockIdx.x % 49;
  const int q0 = qt * 64 + w * 16;

  float pm[9], po[9];
#pragma unroll
  for (int i = 0; i < 9; ++i) { pm[i] = pre[i]; po[i] = post[i]; }

  const short* Qp = Q + ((size_t)b * LQ + q0 + lr) * C_ + lg * 8;
  const short* Kp = K + (size_t)b * LK * C_ + (size_t)lr * C_ + lg * 8;
  const short* Vp = VT + (size_t)b * C_ * VTS;

  s16x8 qf[3][2];
#pragma unroll
  for (int h = 0; h < 3; ++h)
#pragma unroll
    for (int kk = 0; kk < 2; ++kk)
      qf[h][kk] = *(const s16x8*)(Qp + h * 64 + kk * 32);

  const f32x4 zz = {0.f, 0.f, 0.f, 0.f};

  // ---- pass 1: softmax denominators ----
  float lp0 = 0.f, lp1 = 0.f, lp2 = 0.f;
  for (int c = 0; c < 49; ++c) {
    const short* kp = Kp + (size_t)c * 16 * C_;
    s16x8 kf[3][2];
#pragma unroll
    for (int h = 0; h < 3; ++h)
#pragma unroll
      for (int kk = 0; kk < 2; ++kk)
        kf[h][kk] = *(const s16x8*)(kp + h * 64 + kk * 32);
    f32x4 sT[3];
#pragma unroll
    for (int h = 0; h < 3; ++h) {
      sT[h] = __builtin_amdgcn_mfma_f32_16x16x32_bf16(kf[h][0], qf[h][0], zz, 0, 0, 0);
      sT[h] = __builtin_amdgcn_mfma_f32_16x16x32_bf16(kf[h][1], qf[h][1], sT[h], 0, 0, 0);
    }
#pragma unroll
    for (int r = 0; r < 4; ++r) {
      float s0 = sT[0][r], s1 = sT[1][r], s2 = sT[2][r];
      lp0 += __expf(pm[0] * s0 + pm[3] * s1 + pm[6] * s2);
      lp1 += __expf(pm[1] * s0 + pm[4] * s1 + pm[7] * s2);
      lp2 += __expf(pm[2] * s0 + pm[5] * s1 + pm[8] * s2);
    }
  }
  lp0 += __shfl_xor(lp0, 16); lp0 += __shfl_xor(lp0, 32);
  lp1 += __shfl_xor(lp1, 16); lp1 += __shfl_xor(lp1, 32);
  lp2 += __shfl_xor(lp2, 16); lp2 += __shfl_xor(lp2, 32);
  const float li0 = 1.0f / lp0, li1 = 1.0f / lp1, li2 = 1.0f / lp2;

  // ---- pass 2: P and PV ----
  f32x4 o[3][4] = {};
  for (int c = 0; c < 49; ++c) {
    const short* kp = Kp + (size_t)c * 16 * C_;
    s16x8 kf[3][2];
#pragma unroll
    for (int h = 0; h < 3; ++h)
#pragma unroll
      for (int kk = 0; kk < 2; ++kk)
        kf[h][kk] = *(const s16x8*)(kp + h * 64 + kk * 32);
#if HAVE_MFMA16
    s16x4 vf[3][4];
#pragma unroll
    for (int h = 0; h < 3; ++h)
#pragma unroll
      for (int dt = 0; dt < 4; ++dt)
        vf[h][dt] = *(const s16x4*)(Vp + (size_t)(h * 64 + dt * 16 + lr) * VTS + c * 16 + lg * 4);
#else
    s16x8 vf8[3][4];
#pragma unroll
    for (int h = 0; h < 3; ++h)
#pragma unroll
      for (int dt = 0; dt < 4; ++dt)
        vf8[h][dt] = *(const s16x8*)(Vp + (size_t)(h * 64 + dt * 16 + lr) * VTS + c * 16 + lg * 8);
#endif
    f32x4 sT[3];
#pragma unroll
    for (int h = 0; h < 3; ++h) {
      sT[h] = __builtin_amdgcn_mfma_f32_16x16x32_bf16(kf[h][0], qf[h][0], zz, 0, 0, 0);
      sT[h] = __builtin_amdgcn_mfma_f32_16x16x32_bf16(kf[h][1], qf[h][1], sT[h], 0, 0, 0);
    }
    float p0[4], p1[4], p2[4];
#pragma unroll
    for (int r = 0; r < 4; ++r) {
      float s0 = sT[0][r], s1 = sT[1][r], s2 = sT[2][r];
      float e0 = __expf(pm[0] * s0 + pm[3] * s1 + pm[6] * s2) * li0;
      float e1 = __expf(pm[1] * s0 + pm[4] * s1 + pm[7] * s2) * li1;
      float e2 = __expf(pm[2] * s0 + pm[5] * s1 + pm[8] * s2) * li2;
      p0[r] = po[0] * e0 + po[3] * e1 + po[6] * e2;
      p1[r] = po[1] * e0 + po[4] * e1 + po[7] * e2;
      p2[r] = po[2] * e0 + po[5] * e1 + po[8] * e2;
    }
#if HAVE_MFMA16
    s16x4 pa[3];
#pragma unroll
    for (int j = 0; j < 4; ++j) {
      pa[0][j] = (short)f2bf(p0[j]); pa[1][j] = (short)f2bf(p1[j]); pa[2][j] = (short)f2bf(p2[j]);
    }
#pragma unroll
    for (int h = 0; h < 3; ++h)
#pragma unroll
      for (int dt = 0; dt < 4; ++dt)
        o[h][dt] = __builtin_amdgcn_mfma_f32_16x16x16bf16_1k(pa[h], vf[h][dt], o[h][dt], 0, 0, 0);
#else
    // fallback: build half-zero 32-k A-frags via shuffles, use 16x16x32
    union U8 { unsigned int u[4]; s16x8 v; };
    s16x8 pa8[3];
#pragma unroll
    for (int h = 0; h < 3; ++h) {
      float* pp = (h == 0) ? p0 : (h == 1) ? p1 : p2;
      unsigned int P01 = ((unsigned int)f2bf(pp[1]) << 16) | f2bf(pp[0]);
      unsigned int P23 = ((unsigned int)f2bf(pp[3]) << 16) | f2bf(pp[2]);
      int sbase = (lr + 16 * (2 * lg)) & 63;
      U8 u;
      u.u[0] = __shfl(P01, sbase);        u.u[1] = __shfl(P23, sbase);
      u.u[2] = __shfl(P01, (sbase + 16) & 63); u.u[3] = __shfl(P23, (sbase + 16) & 63);
      if (lg >= 2) { u.u[0] = 0; u.u[1] = 0; u.u[2] = 0; u.u[3] = 0; }
      pa8[h] = u.v;
    }
#pragma unroll
    for (int h = 0; h < 3; ++h)
#pragma unroll
      for (int dt = 0; dt < 4; ++dt)
        o[h][dt] = __builtin_amdgcn_mfma_f32_16x16x32_bf16(pa8[h], vf8[h][dt], o[h][dt], 0, 0, 0);
#endif
  }

#pragma unroll
  for (int h = 0; h < 3; ++h)
#pragma unroll
    for (int dt = 0; dt < 4; ++dt)
#pragma unroll
      for (int r = 0; r < 4; ++r)
        Ob[((size_t)b * LQ + q0 + lg * 4 + r) * C_ + h * 64 + dt * 16 + lr] = (short)f2bf(o[h][dt][r]);
}

extern "C" void kernel_launch(void* const* d_in, const int* in_sizes, int n_in,
                              void* d_out, int out_size, void* d_ws, size_t ws_size,
                              hipStream_t stream) {
  (void)in_sizes; (void)n_in; (void)out_size; (void)ws_size;
  const float* inq  = (const float*)d_in[0];
  const float* inkv = (const float*)d_in[1];
  const float* q_dw = (const float*)d_in[2];
  const float* q_sc = (const float*)d_in[3];
  const float* q_bi = (const float*)d_in[4];
  const float* q_me = (const float*)d_in[5];
  const float* q_va = (const float*)d_in[6];
  const float* q_pw = (const float*)d_in[7];
  const float* k_dw = (const float*)d_in[8];
  const float* k_sc = (const float*)d_in[9];
  const float* k_bi = (const float*)d_in[10];
  const float* k_me = (const float*)d_in[11];
  const float* k_va = (const float*)d_in[12];
  const float* k_pw = (const float*)d_in[13];
  const float* v_dw = (const float*)d_in[14];
  const float* v_sc = (const float*)d_in[15];
  const float* v_bi = (const float*)d_in[16];
  const float* v_me = (const float*)d_in[17];
  const float* v_va = (const float*)d_in[18];
  const float* v_pw = (const float*)d_in[19];
  const float* preS  = (const float*)d_in[20];
  const float* postS = (const float*)d_in[21];
  const float* outk  = (const float*)d_in[22];

  short* ws = (short*)d_ws;
  short* qdwb = ws;                       // 8*3136*192
  short* kdwb = qdwb + 4816896;           // 8*784*192
  short* vdwb = kdwb + 1204224;           // 8*784*192
  short* Qb   = vdwb + 1204224;           // 8*3136*192
  short* Kb   = Qb   + 4816896;           // 8*784*192
  short* VTb  = Kb   + 1204224;           // 8*192*800
  short* aout = VTb  + 1228800;           // 8*3136*192
  short* Wt   = aout + 4816896;           // 4*192*192
  short* WtQ = Wt, *WtK = Wt + 36864, *WtV = Wt + 73728, *WtO = Wt + 110592;

  wprep_kernel<<<576, 256, 0, stream>>>(q_pw, k_pw, v_pw, outk, Wt);
  dw_s1_kernel<<<4704, 256, 0, stream>>>(inq, q_dw, q_sc, q_bi, q_me, q_va, qdwb);
  dw_s2_kv_kernel<<<1176, 256, 0, stream>>>(inkv, k_dw, k_sc, k_bi, k_me, k_va,
                                            v_dw, v_sc, v_bi, v_me, v_va, kdwb, vdwb);
  gemm_bf16_kernel<0><<<392, 256, 0, stream>>>(qdwb, WtQ, Qb, 0.125f);
  gemm_bf16_kernel<0><<<98, 256, 0, stream>>>(kdwb, WtK, Kb, 1.0f);
  gemm_bf16_kernel<1><<<98, 256, 0, stream>>>(vdwb, WtV, VTb, 1.0f);
  attn_mfma_kernel<<<392, 256, 0, stream>>>(Qb, Kb, VTb, preS, postS, aout);
  gemm_bf16_kernel<2><<<392, 256, 0, stream>>>(aout, WtO, d_out, 1.0f);
}

// Round 5
// 371.688 us; speedup vs baseline: 4.0610x; 1.0960x over previous
//
#include <hip/hip_runtime.h>
#include <hip/hip_bf16.h>

#define B_   8
#define LQ   3136
#define LK   784
#define C_   192
#define EPSV 1e-5f
#define VTS  800                 // V^T row stride (cols padded 784->800, 16B-aligned)
#define LOG2E 1.4426950408889634f

using f32x4 = __attribute__((ext_vector_type(4))) float;
using s16x8 = __attribute__((ext_vector_type(8))) short;
using s16x4 = __attribute__((ext_vector_type(4))) short;
using us4   = __attribute__((ext_vector_type(4))) unsigned short;

#if __has_builtin(__builtin_amdgcn_mfma_f32_16x16x16bf16_1k)
#define HAVE_MFMA16 1
#else
#define HAVE_MFMA16 0
#endif

static __device__ __forceinline__ unsigned short f2bf(float x) {
  return __builtin_bit_cast(unsigned short, __float2bfloat16(x));
}

// ---------------- merged prep: dw_s1 (blocks 0..4703) + dw_s2 K&V (4704..5879) + wprep (5880..6455) ----
__global__ __launch_bounds__(256) void prep_kernel(
    const float* __restrict__ xq, const float* __restrict__ xkv,
    const float* __restrict__ qdw_w, const float* __restrict__ qsc, const float* __restrict__ qbi,
    const float* __restrict__ qme,  const float* __restrict__ qva,
    const float* __restrict__ kdw_w, const float* __restrict__ ksc, const float* __restrict__ kbi,
    const float* __restrict__ kme,  const float* __restrict__ kva,
    const float* __restrict__ vdw_w, const float* __restrict__ vsc, const float* __restrict__ vbi,
    const float* __restrict__ vme,  const float* __restrict__ vva,
    const float* __restrict__ w0, const float* __restrict__ w1,
    const float* __restrict__ w2, const float* __restrict__ w3,
    short* __restrict__ qy, short* __restrict__ ky, short* __restrict__ vy,
    short* __restrict__ Wt)
{
  const int bid = blockIdx.x;
  if (bid < 4704) {
    // depthwise 3x3 stride-1 + BN -> bf16 (Q path), 4 channels/thread
    int g = bid * 256 + threadIdx.x;                // B*3136*48 exact
    int c4 = (g % 48) * 4; int t = g / 48;
    int xx = t % 56, yy = (t / 56) % 56, b = t / 3136;
    float4 s = {0.f, 0.f, 0.f, 0.f};
#pragma unroll
    for (int dy = 0; dy < 3; ++dy) {
      int iy = yy + dy - 1;
      if (iy < 0 || iy >= 56) continue;
#pragma unroll
      for (int dx = 0; dx < 3; ++dx) {
        int ix = xx + dx - 1;
        if (ix < 0 || ix >= 56) continue;
        float4 xv = *(const float4*)&xq[((size_t)((b * 56 + iy) * 56 + ix)) * C_ + c4];
        float4 wv = *(const float4*)&qdw_w[(dy * 3 + dx) * C_ + c4];
        s.x += xv.x * wv.x; s.y += xv.y * wv.y; s.z += xv.z * wv.z; s.w += xv.w * wv.w;
      }
    }
    float4 scv = *(const float4*)&qsc[c4]; float4 biv = *(const float4*)&qbi[c4];
    float4 mev = *(const float4*)&qme[c4]; float4 vav = *(const float4*)&qva[c4];
    us4 o;
    o[0] = f2bf((s.x - mev.x) * (scv.x * rsqrtf(vav.x + EPSV)) + biv.x);
    o[1] = f2bf((s.y - mev.y) * (scv.y * rsqrtf(vav.y + EPSV)) + biv.y);
    o[2] = f2bf((s.z - mev.z) * (scv.z * rsqrtf(vav.z + EPSV)) + biv.z);
    o[3] = f2bf((s.w - mev.w) * (scv.w * rsqrtf(vav.w + EPSV)) + biv.w);
    *(us4*)&qy[(size_t)t * C_ + c4] = o;
  } else if (bid < 5880) {
    // depthwise 3x3 stride-2 + BN, fused K & V -> bf16
    int g = (bid - 4704) * 256 + threadIdx.x;       // B*784*48 exact
    int c4 = (g % 48) * 4; int t = g / 48;
    int xo = t % 28, yo = (t / 28) % 28, b = t / 784;
    float4 sk = {0.f, 0.f, 0.f, 0.f}, sv = {0.f, 0.f, 0.f, 0.f};
#pragma unroll
    for (int dy = 0; dy < 3; ++dy) {
      int iy = yo * 2 + dy;        // SAME stride-2: pad_lo=0, pad_hi=1
      if (iy >= 56) continue;
#pragma unroll
      for (int dx = 0; dx < 3; ++dx) {
        int ix = xo * 2 + dx;
        if (ix >= 56) continue;
        float4 xv = *(const float4*)&xkv[((size_t)((b * 56 + iy) * 56 + ix)) * C_ + c4];
        float4 kw = *(const float4*)&kdw_w[(dy * 3 + dx) * C_ + c4];
        float4 vw = *(const float4*)&vdw_w[(dy * 3 + dx) * C_ + c4];
        sk.x += xv.x * kw.x; sk.y += xv.y * kw.y; sk.z += xv.z * kw.z; sk.w += xv.w * kw.w;
        sv.x += xv.x * vw.x; sv.y += xv.y * vw.y; sv.z += xv.z * vw.z; sv.w += xv.w * vw.w;
      }
    }
    us4 ko, vo;
#pragma unroll
    for (int j = 0; j < 4; ++j) {
      int c = c4 + j;
      float skj = (j == 0) ? sk.x : (j == 1) ? sk.y : (j == 2) ? sk.z : sk.w;
      float svj = (j == 0) ? sv.x : (j == 1) ? sv.y : (j == 2) ? sv.z : sv.w;
      ko[j] = f2bf((skj - kme[c]) * (ksc[c] * rsqrtf(kva[c] + EPSV)) + kbi[c]);
      vo[j] = f2bf((svj - vme[c]) * (vsc[c] * rsqrtf(vva[c] + EPSV)) + vbi[c]);
    }
    *(us4*)&ky[(size_t)t * C_ + c4] = ko;
    *(us4*)&vy[(size_t)t * C_ + c4] = vo;
  } else {
    // W prep: fp32 [192x192] -> bf16 transposed Wt[n][k], 4 matrices
    int i = (bid - 5880) * 256 + threadIdx.x;       // 4*36864 exact, blocks don't straddle mats
    int m = i / 36864, r = i % 36864;
    int k = r / 192, n = r % 192;
    const float* W = (m == 0) ? w0 : (m == 1) ? w1 : (m == 2) ? w2 : w3;
    Wt[m * 36864 + n * 192 + k] = (short)f2bf(W[r]);
  }
}

// ---------------- bf16 MFMA GEMM core: Y[64 x 192] = X[64 x 192] * Wt^T ----------------
// mode 0: Y bf16 [tok][n] * scale.  mode 1: Y bf16 V^T [b][n][784] stride VTS.
__device__ __forceinline__ void gemm_core(
    const short* __restrict__ X, const short* __restrict__ Wt,
    short* __restrict__ Y, int mode, float scale, int blkrow)
{
  const int tid = threadIdx.x;
  const int w = tid >> 6, lane = tid & 63;
  const int lr = lane & 15, lg = lane >> 4;
  const int rowA = blkrow * 64 + w * 16 + lr;          // A-frag row (m = lane&15)
  const short* Xrow = X + (size_t)rowA * C_ + lg * 8;
  s16x8 af[6];
#pragma unroll
  for (int kk = 0; kk < 6; ++kk) af[kk] = *(const s16x8*)(Xrow + kk * 32);
  f32x4 acc[12] = {};
#pragma unroll
  for (int nt = 0; nt < 12; ++nt) {
    const short* wr = Wt + (size_t)(nt * 16 + lr) * C_ + lg * 8;
#pragma unroll
    for (int kk = 0; kk < 6; ++kk) {
      s16x8 bf_ = *(const s16x8*)(wr + kk * 32);
      acc[nt] = __builtin_amdgcn_mfma_f32_16x16x32_bf16(af[kk], bf_, acc[nt], 0, 0, 0);
    }
  }
  const int tok0 = blkrow * 64 + w * 16 + lg * 4;      // D rows: (lane>>4)*4 + r
#pragma unroll
  for (int nt = 0; nt < 12; ++nt) {
    int n = nt * 16 + lr;
#pragma unroll
    for (int r = 0; r < 4; ++r) {
      int tok = tok0 + r;
      float v = acc[nt][r] * scale;
      if (mode == 0) {
        Y[(size_t)tok * C_ + n] = (short)f2bf(v);
      } else {
        int b = tok / LK, k = tok - b * LK;
        Y[(size_t)b * C_ * VTS + (size_t)n * VTS + k] = (short)f2bf(v);
      }
    }
  }
}

// merged projection GEMMs: blocks 0..391 Q, 392..489 K, 490..587 V
__global__ __launch_bounds__(256) void proj_gemm_kernel(
    const short* __restrict__ qdwb, const short* __restrict__ kdwb, const short* __restrict__ vdwb,
    const short* __restrict__ WtQ, const short* __restrict__ WtK, const short* __restrict__ WtV,
    short* __restrict__ Qb, short* __restrict__ Kb, short* __restrict__ VTb)
{
  const int bid = blockIdx.x;
  if (bid < 392)      gemm_core(qdwb, WtQ, Qb, 0, 0.125f, bid);
  else if (bid < 490) gemm_core(kdwb, WtK, Kb, 0, 1.0f, bid - 392);
  else                gemm_core(vdwb, WtV, VTb, 1, 1.0f, bid - 490);
}

// final out-projection: Y fp32 [tok][n]
__global__ __launch_bounds__(256) void out_gemm_kernel(
    const short* __restrict__ X, const short* __restrict__ Wt, float* __restrict__ Y)
{
  const int tid = threadIdx.x;
  const int w = tid >> 6, lane = tid & 63;
  const int lr = lane & 15, lg = lane >> 4;
  const int rowA = blockIdx.x * 64 + w * 16 + lr;
  const short* Xrow = X + (size_t)rowA * C_ + lg * 8;
  s16x8 af[6];
#pragma unroll
  for (int kk = 0; kk < 6; ++kk) af[kk] = *(const s16x8*)(Xrow + kk * 32);
  f32x4 acc[12] = {};
#pragma unroll
  for (int nt = 0; nt < 12; ++nt) {
    const short* wr = Wt + (size_t)(nt * 16 + lr) * C_ + lg * 8;
#pragma unroll
    for (int kk = 0; kk < 6; ++kk) {
      s16x8 bf_ = *(const s16x8*)(wr + kk * 32);
      acc[nt] = __builtin_amdgcn_mfma_f32_16x16x32_bf16(af[kk], bf_, acc[nt], 0, 0, 0);
    }
  }
  const int tok0 = blockIdx.x * 64 + w * 16 + lg * 4;
#pragma unroll
  for (int nt = 0; nt < 12; ++nt) {
    int n = nt * 16 + lr;
#pragma unroll
    for (int r = 0; r < 4; ++r)
      Y[(size_t)(tok0 + r) * C_ + n] = acc[nt][r];
  }
}

// ---------------- fused head-mixed attention, MFMA, 4-way K-split ----------------
// Block = 4 waves, ALL on the same 16-q tile; wave w takes K-chunks c = w, w+4, ...
// S^T = mfma(K_tile, Q_tile) -> lane holds (q=lane&15, k=(lane>>4)*4+r), which IS the
// 16x16x16 PV A-fragment layout. Denominators reduced via Ls; outputs via Obuf.
__global__ __launch_bounds__(256, 4) void attn_mfma_kernel(
    const short* __restrict__ Q,   // [B][3136][192] bf16, pre-scaled 1/8
    const short* __restrict__ K,   // [B][784][192] bf16
    const short* __restrict__ VT,  // [B][192][VTS] bf16
    const float* __restrict__ pre, const float* __restrict__ post,
    short* __restrict__ Ob)        // [B][3136][192] bf16
{
  __shared__ float Ls[3][16][4];
  __shared__ float Obuf[3][16][192];   // partials from waves 1..3

  const int tid = threadIdx.x;
  const int w = tid >> 6, lane = tid & 63;
  const int lr = lane & 15, lg = lane >> 4;
  const int b = blockIdx.x / 196, qt = blockIdx.x % 196;
  const int q0 = qt * 16;

  float pm[9], po[9];
#pragma unroll
  for (int i = 0; i < 9; ++i) { pm[i] = pre[i] * LOG2E; po[i] = post[i]; }

  const short* Qp = Q + ((size_t)b * LQ + q0 + lr) * C_ + lg * 8;
  const short* Kp = K + (size_t)b * LK * C_ + (size_t)lr * C_ + lg * 8;
  const short* Vp = VT + (size_t)b * C_ * VTS;

  s16x8 qf[3][2];
#pragma unroll
  for (int h = 0; h < 3; ++h)
#pragma unroll
    for (int kk = 0; kk < 2; ++kk)
      qf[h][kk] = *(const s16x8*)(Qp + h * 64 + kk * 32);

  const f32x4 zz = {0.f, 0.f, 0.f, 0.f};

  // ---- pass 1: softmax denominators (partial over this wave's chunks) ----
  float lp0 = 0.f, lp1 = 0.f, lp2 = 0.f;
  for (int c = w; c < 49; c += 4) {
    const short* kp = Kp + (size_t)c * 16 * C_;
    s16x8 kf[3][2];
#pragma unroll
    for (int h = 0; h < 3; ++h)
#pragma unroll
      for (int kk = 0; kk < 2; ++kk)
        kf[h][kk] = *(const s16x8*)(kp + h * 64 + kk * 32);
    f32x4 sT[3];
#pragma unroll
    for (int h = 0; h < 3; ++h) {
      sT[h] = __builtin_amdgcn_mfma_f32_16x16x32_bf16(kf[h][0], qf[h][0], zz, 0, 0, 0);
      sT[h] = __builtin_amdgcn_mfma_f32_16x16x32_bf16(kf[h][1], qf[h][1], sT[h], 0, 0, 0);
    }
#pragma unroll
    for (int r = 0; r < 4; ++r) {
      float s0 = sT[0][r], s1 = sT[1][r], s2 = sT[2][r];
      lp0 += exp2f(pm[0] * s0 + pm[3] * s1 + pm[6] * s2);
      lp1 += exp2f(pm[1] * s0 + pm[4] * s1 + pm[7] * s2);
      lp2 += exp2f(pm[2] * s0 + pm[5] * s1 + pm[8] * s2);
    }
  }
  lp0 += __shfl_xor(lp0, 16); lp0 += __shfl_xor(lp0, 32);
  lp1 += __shfl_xor(lp1, 16); lp1 += __shfl_xor(lp1, 32);
  lp2 += __shfl_xor(lp2, 16); lp2 += __shfl_xor(lp2, 32);
  if (lg == 0) { Ls[0][lr][w] = lp0; Ls[1][lr][w] = lp1; Ls[2][lr][w] = lp2; }
  __syncthreads();
  const float li0 = 1.0f / (Ls[0][lr][0] + Ls[0][lr][1] + Ls[0][lr][2] + Ls[0][lr][3]);
  const float li1 = 1.0f / (Ls[1][lr][0] + Ls[1][lr][1] + Ls[1][lr][2] + Ls[1][lr][3]);
  const float li2 = 1.0f / (Ls[2][lr][0] + Ls[2][lr][1] + Ls[2][lr][2] + Ls[2][lr][3]);

  // ---- pass 2: P and PV (partial over this wave's chunks) ----
  f32x4 o[3][4] = {};
  for (int c = w; c < 49; c += 4) {
    const short* kp = Kp + (size_t)c * 16 * C_;
    s16x8 kf[3][2];
#pragma unroll
    for (int h = 0; h < 3; ++h)
#pragma unroll
      for (int kk = 0; kk < 2; ++kk)
        kf[h][kk] = *(const s16x8*)(kp + h * 64 + kk * 32);
#if HAVE_MFMA16
    s16x4 vf[3][4];
#pragma unroll
    for (int h = 0; h < 3; ++h)
#pragma unroll
      for (int dt = 0; dt < 4; ++dt)
        vf[h][dt] = *(const s16x4*)(Vp + (size_t)(h * 64 + dt * 16 + lr) * VTS + c * 16 + lg * 4);
#else
    s16x8 vf8[3][4];
#pragma unroll
    for (int h = 0; h < 3; ++h)
#pragma unroll
      for (int dt = 0; dt < 4; ++dt)
        vf8[h][dt] = *(const s16x8*)(Vp + (size_t)(h * 64 + dt * 16 + lr) * VTS + c * 16 + lg * 8);
#endif
    f32x4 sT[3];
#pragma unroll
    for (int h = 0; h < 3; ++h) {
      sT[h] = __builtin_amdgcn_mfma_f32_16x16x32_bf16(kf[h][0], qf[h][0], zz, 0, 0, 0);
      sT[h] = __builtin_amdgcn_mfma_f32_16x16x32_bf16(kf[h][1], qf[h][1], sT[h], 0, 0, 0);
    }
    float p0[4], p1[4], p2[4];
#pragma unroll
    for (int r = 0; r < 4; ++r) {
      float s0 = sT[0][r], s1 = sT[1][r], s2 = sT[2][r];
      float e0 = exp2f(pm[0] * s0 + pm[3] * s1 + pm[6] * s2) * li0;
      float e1 = exp2f(pm[1] * s0 + pm[4] * s1 + pm[7] * s2) * li1;
      float e2 = exp2f(pm[2] * s0 + pm[5] * s1 + pm[8] * s2) * li2;
      p0[r] = po[0] * e0 + po[3] * e1 + po[6] * e2;
      p1[r] = po[1] * e0 + po[4] * e1 + po[7] * e2;
      p2[r] = po[2] * e0 + po[5] * e1 + po[8] * e2;
    }
#if HAVE_MFMA16
    s16x4 pa[3];
#pragma unroll
    for (int j = 0; j < 4; ++j) {
      pa[0][j] = (short)f2bf(p0[j]); pa[1][j] = (short)f2bf(p1[j]); pa[2][j] = (short)f2bf(p2[j]);
    }
#pragma unroll
    for (int h = 0; h < 3; ++h)
#pragma unroll
      for (int dt = 0; dt < 4; ++dt)
        o[h][dt] = __builtin_amdgcn_mfma_f32_16x16x16bf16_1k(pa[h], vf[h][dt], o[h][dt], 0, 0, 0);
#else
    union U8 { unsigned int u[4]; s16x8 v; };
    s16x8 pa8[3];
#pragma unroll
    for (int h = 0; h < 3; ++h) {
      float* pp = (h == 0) ? p0 : (h == 1) ? p1 : p2;
      unsigned int P01 = ((unsigned int)f2bf(pp[1]) << 16) | f2bf(pp[0]);
      unsigned int P23 = ((unsigned int)f2bf(pp[3]) << 16) | f2bf(pp[2]);
      int sbase = (lr + 16 * (2 * lg)) & 63;
      U8 u;
      u.u[0] = __shfl(P01, sbase);             u.u[1] = __shfl(P23, sbase);
      u.u[2] = __shfl(P01, (sbase + 16) & 63); u.u[3] = __shfl(P23, (sbase + 16) & 63);
      if (lg >= 2) { u.u[0] = 0; u.u[1] = 0; u.u[2] = 0; u.u[3] = 0; }
      pa8[h] = u.v;
    }
#pragma unroll
    for (int h = 0; h < 3; ++h)
#pragma unroll
      for (int dt = 0; dt < 4; ++dt)
        o[h][dt] = __builtin_amdgcn_mfma_f32_16x16x32_bf16(pa8[h], vf8[h][dt], o[h][dt], 0, 0, 0);
#endif
  }

  // ---- block reduce: waves 1..3 dump partials, wave 0 sums + stores ----
  if (w > 0) {
    float* buf = &Obuf[w - 1][0][0];
#pragma unroll
    for (int h = 0; h < 3; ++h)
#pragma unroll
      for (int dt = 0; dt < 4; ++dt)
#pragma unroll
        for (int r = 0; r < 4; ++r)
          buf[(lg * 4 + r) * 192 + h * 64 + dt * 16 + lr] = o[h][dt][r];
  }
  __syncthreads();
  if (w == 0) {
#pragma unroll
    for (int h = 0; h < 3; ++h)
#pragma unroll
      for (int dt = 0; dt < 4; ++dt)
#pragma unroll
        for (int r = 0; r < 4; ++r) {
          int q = lg * 4 + r, d = h * 64 + dt * 16 + lr;
          float v = o[h][dt][r] + Obuf[0][q][d] + Obuf[1][q][d] + Obuf[2][q][d];
          Ob[((size_t)b * LQ + q0 + q) * C_ + d] = (short)f2bf(v);
        }
  }
}

extern "C" void kernel_launch(void* const* d_in, const int* in_sizes, int n_in,
                              void* d_out, int out_size, void* d_ws, size_t ws_size,
                              hipStream_t stream) {
  (void)in_sizes; (void)n_in; (void)out_size; (void)ws_size;
  const float* inq  = (const float*)d_in[0];
  const float* inkv = (const float*)d_in[1];
  const float* q_dw = (const float*)d_in[2];
  const float* q_sc = (const float*)d_in[3];
  const float* q_bi = (const float*)d_in[4];
  const float* q_me = (const float*)d_in[5];
  const float* q_va = (const float*)d_in[6];
  const float* q_pw = (const float*)d_in[7];
  const float* k_dw = (const float*)d_in[8];
  const float* k_sc = (const float*)d_in[9];
  const float* k_bi = (const float*)d_in[10];
  const float* k_me = (const float*)d_in[11];
  const float* k_va = (const float*)d_in[12];
  const float* k_pw = (const float*)d_in[13];
  const float* v_dw = (const float*)d_in[14];
  const float* v_sc = (const float*)d_in[15];
  const float* v_bi = (const float*)d_in[16];
  const float* v_me = (const float*)d_in[17];
  const float* v_va = (const float*)d_in[18];
  const float* v_pw = (const float*)d_in[19];
  const float* preS  = (const float*)d_in[20];
  const float* postS = (const float*)d_in[21];
  const float* outk  = (const float*)d_in[22];

  short* ws = (short*)d_ws;
  short* qdwb = ws;                       // 8*3136*192
  short* kdwb = qdwb + 4816896;           // 8*784*192
  short* vdwb = kdwb + 1204224;           // 8*784*192
  short* Qb   = vdwb + 1204224;           // 8*3136*192
  short* Kb   = Qb   + 4816896;           // 8*784*192
  short* VTb  = Kb   + 1204224;           // 8*192*800
  short* aout = VTb  + 1228800;           // 8*3136*192
  short* Wt   = aout + 4816896;           // 4*192*192
  short* WtQ = Wt, *WtK = Wt + 36864, *WtV = Wt + 73728, *WtO = Wt + 110592;

  prep_kernel<<<6456, 256, 0, stream>>>(
      inq, inkv,
      q_dw, q_sc, q_bi, q_me, q_va,
      k_dw, k_sc, k_bi, k_me, k_va,
      v_dw, v_sc, v_bi, v_me, v_va,
      q_pw, k_pw, v_pw, outk,
      qdwb, kdwb, vdwb, Wt);
  proj_gemm_kernel<<<588, 256, 0, stream>>>(qdwb, kdwb, vdwb, WtQ, WtK, WtV, Qb, Kb, VTb);
  attn_mfma_kernel<<<1568, 256, 0, stream>>>(Qb, Kb, VTb, preS, postS, aout);
  out_gemm_kernel<<<392, 256, 0, stream>>>(aout, WtO, (float*)d_out);
}

// Round 6
// 288.508 us; speedup vs baseline: 5.2318x; 1.2883x over previous
//
#include <hip/hip_runtime.h>
#include <hip/hip_bf16.h>

#define B_   8
#define LQ   3136
#define LK   784
#define C_   192
#define NCH  49
#define EPSV 1e-5f
#define LOG2E 1.4426950408889634f

using f32x4 = __attribute__((ext_vector_type(4))) float;
using s16x8 = __attribute__((ext_vector_type(8))) short;
using s16x4 = __attribute__((ext_vector_type(4))) short;
using us4   = __attribute__((ext_vector_type(4))) unsigned short;

#if __has_builtin(__builtin_amdgcn_mfma_f32_16x16x16bf16_1k)
#define HAVE_MFMA16 1
#else
#define HAVE_MFMA16 0
#endif

static __device__ __forceinline__ unsigned short f2bf(float x) {
  return __builtin_bit_cast(unsigned short, __float2bfloat16(x));
}

// ---------------- merged prep: dw_s1 (blocks 0..4703) + dw_s2 K&V (4704..5879) + wprep (5880..6455) ----
__global__ __launch_bounds__(256) void prep_kernel(
    const float* __restrict__ xq, const float* __restrict__ xkv,
    const float* __restrict__ qdw_w, const float* __restrict__ qsc, const float* __restrict__ qbi,
    const float* __restrict__ qme,  const float* __restrict__ qva,
    const float* __restrict__ kdw_w, const float* __restrict__ ksc, const float* __restrict__ kbi,
    const float* __restrict__ kme,  const float* __restrict__ kva,
    const float* __restrict__ vdw_w, const float* __restrict__ vsc, const float* __restrict__ vbi,
    const float* __restrict__ vme,  const float* __restrict__ vva,
    const float* __restrict__ w0, const float* __restrict__ w1,
    const float* __restrict__ w2, const float* __restrict__ w3,
    short* __restrict__ qy, short* __restrict__ ky, short* __restrict__ vy,
    short* __restrict__ Wt)
{
  const int bid = blockIdx.x;
  if (bid < 4704) {
    int g = bid * 256 + threadIdx.x;                // B*3136*48 exact
    int c4 = (g % 48) * 4; int t = g / 48;
    int xx = t % 56, yy = (t / 56) % 56, b = t / 3136;
    float4 s = {0.f, 0.f, 0.f, 0.f};
#pragma unroll
    for (int dy = 0; dy < 3; ++dy) {
      int iy = yy + dy - 1;
      if (iy < 0 || iy >= 56) continue;
#pragma unroll
      for (int dx = 0; dx < 3; ++dx) {
        int ix = xx + dx - 1;
        if (ix < 0 || ix >= 56) continue;
        float4 xv = *(const float4*)&xq[((size_t)((b * 56 + iy) * 56 + ix)) * C_ + c4];
        float4 wv = *(const float4*)&qdw_w[(dy * 3 + dx) * C_ + c4];
        s.x += xv.x * wv.x; s.y += xv.y * wv.y; s.z += xv.z * wv.z; s.w += xv.w * wv.w;
      }
    }
    float4 scv = *(const float4*)&qsc[c4]; float4 biv = *(const float4*)&qbi[c4];
    float4 mev = *(const float4*)&qme[c4]; float4 vav = *(const float4*)&qva[c4];
    us4 o;
    o[0] = f2bf((s.x - mev.x) * (scv.x * rsqrtf(vav.x + EPSV)) + biv.x);
    o[1] = f2bf((s.y - mev.y) * (scv.y * rsqrtf(vav.y + EPSV)) + biv.y);
    o[2] = f2bf((s.z - mev.z) * (scv.z * rsqrtf(vav.z + EPSV)) + biv.z);
    o[3] = f2bf((s.w - mev.w) * (scv.w * rsqrtf(vav.w + EPSV)) + biv.w);
    *(us4*)&qy[(size_t)t * C_ + c4] = o;
  } else if (bid < 5880) {
    int g = (bid - 4704) * 256 + threadIdx.x;       // B*784*48 exact
    int c4 = (g % 48) * 4; int t = g / 48;
    int xo = t % 28, yo = (t / 28) % 28, b = t / 784;
    float4 sk = {0.f, 0.f, 0.f, 0.f}, sv = {0.f, 0.f, 0.f, 0.f};
#pragma unroll
    for (int dy = 0; dy < 3; ++dy) {
      int iy = yo * 2 + dy;        // SAME stride-2: pad_lo=0, pad_hi=1
      if (iy >= 56) continue;
#pragma unroll
      for (int dx = 0; dx < 3; ++dx) {
        int ix = xo * 2 + dx;
        if (ix >= 56) continue;
        float4 xv = *(const float4*)&xkv[((size_t)((b * 56 + iy) * 56 + ix)) * C_ + c4];
        float4 kw = *(const float4*)&kdw_w[(dy * 3 + dx) * C_ + c4];
        float4 vw = *(const float4*)&vdw_w[(dy * 3 + dx) * C_ + c4];
        sk.x += xv.x * kw.x; sk.y += xv.y * kw.y; sk.z += xv.z * kw.z; sk.w += xv.w * kw.w;
        sv.x += xv.x * vw.x; sv.y += xv.y * vw.y; sv.z += xv.z * vw.z; sv.w += xv.w * vw.w;
      }
    }
    us4 ko, vo;
#pragma unroll
    for (int j = 0; j < 4; ++j) {
      int c = c4 + j;
      float skj = (j == 0) ? sk.x : (j == 1) ? sk.y : (j == 2) ? sk.z : sk.w;
      float svj = (j == 0) ? sv.x : (j == 1) ? sv.y : (j == 2) ? sv.z : sv.w;
      ko[j] = f2bf((skj - kme[c]) * (ksc[c] * rsqrtf(kva[c] + EPSV)) + kbi[c]);
      vo[j] = f2bf((svj - vme[c]) * (vsc[c] * rsqrtf(vva[c] + EPSV)) + vbi[c]);
    }
    *(us4*)&ky[(size_t)t * C_ + c4] = ko;
    *(us4*)&vy[(size_t)t * C_ + c4] = vo;
  } else {
    int i = (bid - 5880) * 256 + threadIdx.x;       // 4*36864 exact
    int m = i / 36864, r = i % 36864;
    int k = r / 192, n = r % 192;
    const float* W = (m == 0) ? w0 : (m == 1) ? w1 : (m == 2) ? w2 : w3;
    Wt[m * 36864 + n * 192 + k] = (short)f2bf(W[r]);
  }
}

// ---------------- bf16 MFMA GEMM core: Y[64 x 192] = X[64 x 192] * Wt^T ----------------
// mode 0: Y bf16 [tok][n] * scale.  mode 1: Y bf16 tiled V^T [b][chunk49][d 192][k 16].
__device__ __forceinline__ void gemm_core(
    const short* __restrict__ X, const short* __restrict__ Wt,
    short* __restrict__ Y, int mode, float scale, int blkrow)
{
  const int tid = threadIdx.x;
  const int w = tid >> 6, lane = tid & 63;
  const int lr = lane & 15, lg = lane >> 4;
  const int rowA = blkrow * 64 + w * 16 + lr;          // A-frag row (m = lane&15)
  const short* Xrow = X + (size_t)rowA * C_ + lg * 8;
  s16x8 af[6];
#pragma unroll
  for (int kk = 0; kk < 6; ++kk) af[kk] = *(const s16x8*)(Xrow + kk * 32);
  f32x4 acc[12] = {};
#pragma unroll
  for (int nt = 0; nt < 12; ++nt) {
    const short* wr = Wt + (size_t)(nt * 16 + lr) * C_ + lg * 8;
#pragma unroll
    for (int kk = 0; kk < 6; ++kk) {
      s16x8 bf_ = *(const s16x8*)(wr + kk * 32);
      acc[nt] = __builtin_amdgcn_mfma_f32_16x16x32_bf16(af[kk], bf_, acc[nt], 0, 0, 0);
    }
  }
  const int tok0 = blkrow * 64 + w * 16 + lg * 4;      // D rows: (lane>>4)*4 + r
#pragma unroll
  for (int nt = 0; nt < 12; ++nt) {
    int n = nt * 16 + lr;
    if (mode == 1) {
      int bb = tok0 / LK, k0 = tok0 - bb * LK;   // tok0..tok0+3 within same batch & chunk
      int ch = k0 >> 4, kk = k0 & 15;
      us4 pk;
#pragma unroll
      for (int r = 0; r < 4; ++r) pk[r] = f2bf(acc[nt][r] * scale);
      *(us4*)&Y[((size_t)bb * NCH + ch) * 3072 + n * 16 + kk] = pk;
    } else {
#pragma unroll
      for (int r = 0; r < 4; ++r) {
        int tok = tok0 + r;
        Y[(size_t)tok * C_ + n] = (short)f2bf(acc[nt][r] * scale);
      }
    }
  }
}

// merged projection GEMMs: blocks 0..391 Q, 392..489 K, 490..587 V
__global__ __launch_bounds__(256) void proj_gemm_kernel(
    const short* __restrict__ qdwb, const short* __restrict__ kdwb, const short* __restrict__ vdwb,
    const short* __restrict__ WtQ, const short* __restrict__ WtK, const short* __restrict__ WtV,
    short* __restrict__ Qb, short* __restrict__ Kb, short* __restrict__ VTb)
{
  const int bid = blockIdx.x;
  if (bid < 392)      gemm_core(qdwb, WtQ, Qb, 0, 0.125f, bid);
  else if (bid < 490) gemm_core(kdwb, WtK, Kb, 0, 1.0f, bid - 392);
  else                gemm_core(vdwb, WtV, VTb, 1, 1.0f, bid - 490);
}

// final out-projection: Y fp32 [tok][n]
__global__ __launch_bounds__(256) void out_gemm_kernel(
    const short* __restrict__ X, const short* __restrict__ Wt, float* __restrict__ Y)
{
  const int tid = threadIdx.x;
  const int w = tid >> 6, lane = tid & 63;
  const int lr = lane & 15, lg = lane >> 4;
  const int rowA = blockIdx.x * 64 + w * 16 + lr;
  const short* Xrow = X + (size_t)rowA * C_ + lg * 8;
  s16x8 af[6];
#pragma unroll
  for (int kk = 0; kk < 6; ++kk) af[kk] = *(const s16x8*)(Xrow + kk * 32);
  f32x4 acc[12] = {};
#pragma unroll
  for (int nt = 0; nt < 12; ++nt) {
    const short* wr = Wt + (size_t)(nt * 16 + lr) * C_ + lg * 8;
#pragma unroll
    for (int kk = 0; kk < 6; ++kk) {
      s16x8 bf_ = *(const s16x8*)(wr + kk * 32);
      acc[nt] = __builtin_amdgcn_mfma_f32_16x16x32_bf16(af[kk], bf_, acc[nt], 0, 0, 0);
    }
  }
  const int tok0 = blockIdx.x * 64 + w * 16 + lg * 4;
#pragma unroll
  for (int nt = 0; nt < 12; ++nt) {
    int n = nt * 16 + lr;
#pragma unroll
    for (int r = 0; r < 4; ++r)
      Y[(size_t)(tok0 + r) * C_ + n] = acc[nt][r];
  }
}

// ---------------- fused head-mixed attention: 4 waves share LDS-staged K/V, 64q/block ----------------
// Wave w owns q-rows [qt*64 + w*16, +16). All waves iterate ALL 49 k-chunks (no K-split, no reduce).
// K LDS layout: fragment-order 16B units u=(f=h*2+kk, k, lg) at u*16B -> ds_read_b128 optimal.
// V LDS layout: linear copy of tiled global V^T chunk [192 d][16 k]; vf b64 at unit (h*4+dt, lr, lg).
__global__ __launch_bounds__(256, 2) void attn_mfma_kernel(
    const short* __restrict__ Q,   // [B][3136][192] bf16, pre-scaled 1/8
    const short* __restrict__ K,   // [B][784][192] bf16
    const short* __restrict__ VTt, // [B][49][192][16] bf16 tiled
    const float* __restrict__ pre, const float* __restrict__ post,
    short* __restrict__ Ob)        // [B][3136][192] bf16
{
  __shared__ short Klds[2][3072];
  __shared__ short Vlds[2][3072];

  const int tid = threadIdx.x;
  const int lane = tid & 63, w = tid >> 6;
  const int lr = lane & 15, lg = lane >> 4;
  const int b = blockIdx.x / NCH, qt = blockIdx.x % NCH;
  const int q0 = qt * 64 + w * 16;

  float pm[9], po[9];
#pragma unroll
  for (int i = 0; i < 9; ++i) { pm[i] = pre[i] * LOG2E; po[i] = post[i]; }

  const short* Kg = K + (size_t)b * LK * C_;
  const short* Vg = VTt + (size_t)b * NCH * 3072;

  // K staging geometry: unit u -> f=u>>6, krow=(u>>2)&15, lgu=u&3
  const int u0 = tid, u1 = tid + 256;
  const int f0 = u0 >> 6, f1 = u1 >> 6;
  const int kg0 = ((u0 >> 2) & 15) * C_ + ((f0 >> 1) << 6) + ((f0 & 1) << 5) + ((u0 & 3) << 3);
  const int kg1 = ((u1 >> 2) & 15) * C_ + ((f1 >> 1) << 6) + ((f1 & 1) << 5) + ((u1 & 3) << 3);

  // Q fragments (held for whole kernel)
  const short* Qp = Q + ((size_t)b * LQ + q0 + lr) * C_ + lg * 8;
  s16x8 qf[3][2];
#pragma unroll
  for (int h = 0; h < 3; ++h)
#pragma unroll
    for (int kk = 0; kk < 2; ++kk)
      qf[h][kk] = *(const s16x8*)(Qp + h * 64 + kk * 32);

  const f32x4 zz = {0.f, 0.f, 0.f, 0.f};

  // ================= pass 1: softmax denominators =================
  float lp0 = 0.f, lp1 = 0.f, lp2 = 0.f;
  {
    *(s16x8*)&Klds[0][u0 * 8] = *(const s16x8*)(Kg + kg0);
    if (tid < 128) *(s16x8*)&Klds[0][u1 * 8] = *(const s16x8*)(Kg + kg1);
  }
  __syncthreads();
  for (int c = 0; c < NCH; ++c) {
    s16x8 kr0, kr1;
    const bool pf = (c + 1 < NCH);
    if (pf) {                                   // issue next-chunk loads early (T14 split)
      const short* g = Kg + (size_t)(c + 1) * 16 * C_;
      kr0 = *(const s16x8*)(g + kg0);
      if (tid < 128) kr1 = *(const s16x8*)(g + kg1);
    }
    const short* kb = Klds[c & 1];
    s16x8 kf[6];
#pragma unroll
    for (int f = 0; f < 6; ++f)
      kf[f] = *(const s16x8*)&kb[(f * 64 + lr * 4 + lg) * 8];
    f32x4 sT[3];
#pragma unroll
    for (int h = 0; h < 3; ++h) {
      sT[h] = __builtin_amdgcn_mfma_f32_16x16x32_bf16(kf[h * 2], qf[h][0], zz, 0, 0, 0);
      sT[h] = __builtin_amdgcn_mfma_f32_16x16x32_bf16(kf[h * 2 + 1], qf[h][1], sT[h], 0, 0, 0);
    }
#pragma unroll
    for (int r = 0; r < 4; ++r) {
      float s0 = sT[0][r], s1 = sT[1][r], s2 = sT[2][r];
      lp0 += exp2f(pm[0] * s0 + pm[3] * s1 + pm[6] * s2);
      lp1 += exp2f(pm[1] * s0 + pm[4] * s1 + pm[7] * s2);
      lp2 += exp2f(pm[2] * s0 + pm[5] * s1 + pm[8] * s2);
    }
    if (pf) {
      short* kd = Klds[(c + 1) & 1];
      *(s16x8*)&kd[u0 * 8] = kr0;
      if (tid < 128) *(s16x8*)&kd[u1 * 8] = kr1;
    }
    __syncthreads();
  }
  lp0 += __shfl_xor(lp0, 16); lp0 += __shfl_xor(lp0, 32);
  lp1 += __shfl_xor(lp1, 16); lp1 += __shfl_xor(lp1, 32);
  lp2 += __shfl_xor(lp2, 16); lp2 += __shfl_xor(lp2, 32);
  const float li0 = 1.0f / lp0, li1 = 1.0f / lp1, li2 = 1.0f / lp2;
  float poli[9];
#pragma unroll
  for (int h = 0; h < 3; ++h) {
    poli[h]     = po[h]     * li0;
    poli[3 + h] = po[3 + h] * li1;
    poli[6 + h] = po[6 + h] * li2;
  }

  // ================= pass 2: P and PV =================
  {
    *(s16x8*)&Klds[0][u0 * 8] = *(const s16x8*)(Kg + kg0);
    if (tid < 128) *(s16x8*)&Klds[0][u1 * 8] = *(const s16x8*)(Kg + kg1);
#pragma unroll
    for (int t = 0; t < 3; ++t) {
      int v = tid + t * 256;
      *(s16x4*)&Vlds[0][v * 4] = *(const s16x4*)(Vg + v * 4);
    }
  }
  __syncthreads();

  f32x4 o[3][4] = {};
  for (int c = 0; c < NCH; ++c) {
    s16x8 kr0, kr1; s16x4 vr[3];
    const bool pf = (c + 1 < NCH);
    if (pf) {
      const short* g = Kg + (size_t)(c + 1) * 16 * C_;
      kr0 = *(const s16x8*)(g + kg0);
      if (tid < 128) kr1 = *(const s16x8*)(g + kg1);
      const short* gv = Vg + (size_t)(c + 1) * 3072;
#pragma unroll
      for (int t = 0; t < 3; ++t)
        vr[t] = *(const s16x4*)(gv + (tid + t * 256) * 4);
    }
    const short* kb = Klds[c & 1];
    const short* vb = Vlds[c & 1];
    s16x8 kf[6];
#pragma unroll
    for (int f = 0; f < 6; ++f)
      kf[f] = *(const s16x8*)&kb[(f * 64 + lr * 4 + lg) * 8];
    f32x4 sT[3];
#pragma unroll
    for (int h = 0; h < 3; ++h) {
      sT[h] = __builtin_amdgcn_mfma_f32_16x16x32_bf16(kf[h * 2], qf[h][0], zz, 0, 0, 0);
      sT[h] = __builtin_amdgcn_mfma_f32_16x16x32_bf16(kf[h * 2 + 1], qf[h][1], sT[h], 0, 0, 0);
    }
    float p0[4], p1[4], p2[4];
#pragma unroll
    for (int r = 0; r < 4; ++r) {
      float s0 = sT[0][r], s1 = sT[1][r], s2 = sT[2][r];
      float e0 = exp2f(pm[0] * s0 + pm[3] * s1 + pm[6] * s2);
      float e1 = exp2f(pm[1] * s0 + pm[4] * s1 + pm[7] * s2);
      float e2 = exp2f(pm[2] * s0 + pm[5] * s1 + pm[8] * s2);
      p0[r] = poli[0] * e0 + poli[3] * e1 + poli[6] * e2;
      p1[r] = poli[1] * e0 + poli[4] * e1 + poli[7] * e2;
      p2[r] = poli[2] * e0 + poli[5] * e1 + poli[8] * e2;
    }
#if HAVE_MFMA16
    s16x4 pa[3];
#pragma unroll
    for (int j = 0; j < 4; ++j) {
      pa[0][j] = (short)f2bf(p0[j]); pa[1][j] = (short)f2bf(p1[j]); pa[2][j] = (short)f2bf(p2[j]);
    }
    s16x4 vf[12];
#pragma unroll
    for (int hd = 0; hd < 12; ++hd)
      vf[hd] = *(const s16x4*)&vb[(hd * 64 + lr * 4 + lg) * 4];
#pragma unroll
    for (int h = 0; h < 3; ++h)
#pragma unroll
      for (int dt = 0; dt < 4; ++dt)
        o[h][dt] = __builtin_amdgcn_mfma_f32_16x16x16bf16_1k(pa[h], vf[h * 4 + dt], o[h][dt], 0, 0, 0);
#else
    // fallback: 16x16x32 with upper-half-zero A; vf8 reads k 0..15 for lg<2 (others don't-care)
    union U8 { unsigned int u[4]; s16x8 v; };
    s16x8 pa8[3];
#pragma unroll
    for (int h = 0; h < 3; ++h) {
      float* pp = (h == 0) ? p0 : (h == 1) ? p1 : p2;
      unsigned int P01 = ((unsigned int)f2bf(pp[1]) << 16) | f2bf(pp[0]);
      unsigned int P23 = ((unsigned int)f2bf(pp[3]) << 16) | f2bf(pp[2]);
      int sbase = (lr + 16 * (2 * lg)) & 63;
      U8 u;
      u.u[0] = __shfl(P01, sbase);             u.u[1] = __shfl(P23, sbase);
      u.u[2] = __shfl(P01, (sbase + 16) & 63); u.u[3] = __shfl(P23, (sbase + 16) & 63);
      if (lg >= 2) { u.u[0] = 0; u.u[1] = 0; u.u[2] = 0; u.u[3] = 0; }
      pa8[h] = u.v;
    }
    s16x8 vf8[12];
#pragma unroll
    for (int hd = 0; hd < 12; ++hd)
      vf8[hd] = *(const s16x8*)&vb[(hd * 64 + lr * 4 + (lg & 1) * 2) * 4];
#pragma unroll
    for (int h = 0; h < 3; ++h)
#pragma unroll
      for (int dt = 0; dt < 4; ++dt)
        o[h][dt] = __builtin_amdgcn_mfma_f32_16x16x32_bf16(pa8[h], vf8[h * 4 + dt], o[h][dt], 0, 0, 0);
#endif
    if (pf) {
      short* kd = Klds[(c + 1) & 1];
      *(s16x8*)&kd[u0 * 8] = kr0;
      if (tid < 128) *(s16x8*)&kd[u1 * 8] = kr1;
      short* vd = Vlds[(c + 1) & 1];
#pragma unroll
      for (int t = 0; t < 3; ++t)
        *(s16x4*)&vd[(tid + t * 256) * 4] = vr[t];
    }
    __syncthreads();
  }

#pragma unroll
  for (int h = 0; h < 3; ++h)
#pragma unroll
    for (int dt = 0; dt < 4; ++dt)
#pragma unroll
      for (int r = 0; r < 4; ++r)
        Ob[((size_t)b * LQ + q0 + lg * 4 + r) * C_ + h * 64 + dt * 16 + lr] = (short)f2bf(o[h][dt][r]);
}

extern "C" void kernel_launch(void* const* d_in, const int* in_sizes, int n_in,
                              void* d_out, int out_size, void* d_ws, size_t ws_size,
                              hipStream_t stream) {
  (void)in_sizes; (void)n_in; (void)out_size; (void)ws_size;
  const float* inq  = (const float*)d_in[0];
  const float* inkv = (const float*)d_in[1];
  const float* q_dw = (const float*)d_in[2];
  const float* q_sc = (const float*)d_in[3];
  const float* q_bi = (const float*)d_in[4];
  const float* q_me = (const float*)d_in[5];
  const float* q_va = (const float*)d_in[6];
  const float* q_pw = (const float*)d_in[7];
  const float* k_dw = (const float*)d_in[8];
  const float* k_sc = (const float*)d_in[9];
  const float* k_bi = (const float*)d_in[10];
  const float* k_me = (const float*)d_in[11];
  const float* k_va = (const float*)d_in[12];
  const float* k_pw = (const float*)d_in[13];
  const float* v_dw = (const float*)d_in[14];
  const float* v_sc = (const float*)d_in[15];
  const float* v_bi = (const float*)d_in[16];
  const float* v_me = (const float*)d_in[17];
  const float* v_va = (const float*)d_in[18];
  const float* v_pw = (const float*)d_in[19];
  const float* preS  = (const float*)d_in[20];
  const float* postS = (const float*)d_in[21];
  const float* outk  = (const float*)d_in[22];

  short* ws = (short*)d_ws;
  short* qdwb = ws;                       // 8*3136*192
  short* kdwb = qdwb + 4816896;           // 8*784*192
  short* vdwb = kdwb + 1204224;           // 8*784*192
  short* Qb   = vdwb + 1204224;           // 8*3136*192
  short* Kb   = Qb   + 4816896;           // 8*784*192
  short* VTb  = Kb   + 1204224;           // 8*49*192*16 tiled (slot sized 1228800)
  short* aout = VTb  + 1228800;           // 8*3136*192
  short* Wt   = aout + 4816896;           // 4*192*192
  short* WtQ = Wt, *WtK = Wt + 36864, *WtV = Wt + 73728, *WtO = Wt + 110592;

  prep_kernel<<<6456, 256, 0, stream>>>(
      inq, inkv,
      q_dw, q_sc, q_bi, q_me, q_va,
      k_dw, k_sc, k_bi, k_me, k_va,
      v_dw, v_sc, v_bi, v_me, v_va,
      q_pw, k_pw, v_pw, outk,
      qdwb, kdwb, vdwb, Wt);
  proj_gemm_kernel<<<588, 256, 0, stream>>>(qdwb, kdwb, vdwb, WtQ, WtK, WtV, Qb, Kb, VTb);
  attn_mfma_kernel<<<392, 256, 0, stream>>>(Qb, Kb, VTb, preS, postS, aout);
  out_gemm_kernel<<<392, 256, 0, stream>>>(aout, WtO, (float*)d_out);
}